// Round 2
// baseline (366.194 us; speedup 1.0000x reference)
//
#include <hip/hip_runtime.h>

typedef __attribute__((ext_vector_type(8))) short short8;   // 8 bf16 = 4 VGPRs
typedef __attribute__((ext_vector_type(4))) float float4v;  // 4 fp32
typedef __attribute__((ext_vector_type(4))) short short4v;  // 4 bf16

#define LDSROW 136  // shorts per Wt row: 128 + 8 pad -> 272 B stride

static __device__ inline short f2bf(float f) {
    union { float f; unsigned u; } v; v.f = f;
    unsigned u = v.u;
    u += 0x7fffu + ((u >> 16) & 1u);   // round-to-nearest-even
    return (short)(u >> 16);
}

// out[b, n'] = sum_k' A[b, k'] * W[k', n']
//   A row (contiguous): k'<64 -> xr[k'] (pilot->1), k'>=64 -> xi[k'-64] (pilot->0)
//   W[k'][n'] = [[cos, sin], [-sin, cos]] (cos/sin symmetric 64x64, scaled 1/64)
//
// Occupancy design: 512 thr/block (8 waves), LDS 34816 B -> 4 blocks/CU,
// VGPR capped at 64 via __launch_bounds__(512,8) -> 32 waves/CU (100%).
// Grid 1024 blocks = exactly 4 resident blocks per CU; 2 tiles per wave.
__global__ __launch_bounds__(512, 8)
void ofdm_idft_kernel(const float* __restrict__ eq,
                      const float* __restrict__ cosk,
                      const float* __restrict__ sink,
                      float* __restrict__ out)
{
    __shared__ short Wt[128 * LDSROW];  // Wt[n'][k'] = W[k'][n'] bf16, 34816 B

    const int tid = threadIdx.x;

    // ---- Build Wt, vectorized: 4096 float4-groups, 8 iters/thread ----
    for (int g = tid; g < 4096; g += 512) {
        const int n  = g >> 5;          // 0..127 (output col)
        const int k4 = (g & 31) * 4;    // 0,4,...,124 (input k, groups of 4)
        const int nn = n & 63;
        const int km = k4 & 63;         // k4 multiple of 4, so &63 == -64 when >=64
        const float* src;
        float sgn = 1.0f;
        if (n < 64) {
            if (k4 < 64) { src = cosk; } else { src = sink; sgn = -1.0f; }
        } else {
            if (k4 < 64) { src = sink; } else { src = cosk; }
        }
        const float4v v = *(const float4v*)(src + nn * 64 + km);
        short4v s;
        #pragma unroll
        for (int j = 0; j < 4; ++j) s[j] = f2bf(sgn * v[j]);
        *(short4v*)&Wt[n * LDSROW + k4] = s;   // 8B-aligned: 272n + 8*(k4/4)
    }
    __syncthreads();

    const int lane = tid & 63;
    const int wave = tid >> 6;
    const int m    = lane & 15;   // M row / N col within tile
    const int q    = lane >> 4;   // quad: k-offset for frags, row-group for D

    const unsigned long long PMASK =
        (1ull << 11) | (1ull << 25) | (1ull << 39) | (1ull << 53);

    const int wave_id = blockIdx.x * 8 + wave;   // 8192 waves, 32 batches each

    for (int t = 0; t < 2; ++t) {
        const int b0 = wave_id * 32 + t * 16;
        const float* arow = eq + (size_t)(b0 + m) * 128;

        // ---- A fragments: A[m = lane&15][k = kk*32 + q*8 + j], j=0..7 ----
        short8 afrag[4];
        #pragma unroll
        for (int kk = 0; kk < 4; ++kk) {
            const int kbase = kk * 32 + q * 8;
            const float4v x0 = *(const float4v*)(arow + kbase);
            const float4v x1 = *(const float4v*)(arow + kbase + 4);
            short8 f;
            #pragma unroll
            for (int j = 0; j < 8; ++j) {
                float xv = (j < 4) ? x0[j] : x1[j - 4];
                const int k = kbase + j;
                if ((PMASK >> (k & 63)) & 1ull)
                    xv = (k < 64) ? 1.0f : 0.0f;   // pilot: real->1, imag->0
                f[j] = f2bf(xv);
            }
            afrag[kk] = f;
        }

        // ---- MFMA: 8 n-tiles x 4 k-steps ----
        float4v acc[8];
        #pragma unroll
        for (int nt = 0; nt < 8; ++nt) acc[nt] = (float4v){0.f, 0.f, 0.f, 0.f};

        #pragma unroll
        for (int kk = 0; kk < 4; ++kk) {
            #pragma unroll
            for (int nt = 0; nt < 8; ++nt) {
                const short8 bfrag =
                    *(const short8*)&Wt[(nt * 16 + m) * LDSROW + kk * 32 + q * 8];
                acc[nt] = __builtin_amdgcn_mfma_f32_16x16x32_bf16(
                    afrag[kk], bfrag, acc[nt], 0, 0, 0);
            }
        }

        // ---- Store: D[row = q*4 + r][col = nt*16 + m]; nt inner so the two
        // 64B halves of each 128B line issue adjacently ----
        float* orow = out + (size_t)b0 * 128;
        #pragma unroll
        for (int r = 0; r < 4; ++r) {
            #pragma unroll
            for (int nt = 0; nt < 8; ++nt) {
                orow[(size_t)(q * 4 + r) * 128 + nt * 16 + m] = acc[nt][r];
            }
        }
    }
}

extern "C" void kernel_launch(void* const* d_in, const int* in_sizes, int n_in,
                              void* d_out, int out_size, void* d_ws, size_t ws_size,
                              hipStream_t stream) {
    const float* eq   = (const float*)d_in[0];
    const float* cosk = (const float*)d_in[1];
    const float* sink = (const float*)d_in[2];
    float* out = (float*)d_out;
    // 1024 blocks * 8 waves * 2 tiles * 16 = 262144 batches, exact cover
    hipLaunchKernelGGL(ofdm_idft_kernel, dim3(1024), dim3(512), 0, stream,
                       eq, cosk, sink, out);
}

// Round 3
// 257.367 us; speedup vs baseline: 1.4228x; 1.4228x over previous
//
#include <hip/hip_runtime.h>

typedef __attribute__((ext_vector_type(8))) short short8;   // 8 bf16 = 4 VGPRs
typedef __attribute__((ext_vector_type(4))) float float4v;  // 4 fp32

static __device__ inline short f2bf(float f) {
    union { float f; unsigned u; } v; v.f = f;
    unsigned u = v.u;
    u += 0x7fffu + ((u >> 16) & 1u);   // round-to-nearest-even
    return (short)(u >> 16);
}

// Setup: Wt[n][k] = W[k][n] in bf16, row-major stride 128, written to d_ws.
// W[k][n] = [[cos, sin], [-sin, cos]] (cos/sin symmetric 64x64, scaled 1/64).
// 64 blocks x 256 thr = 16384 threads, one element each.
__global__ __launch_bounds__(256)
void build_wt(const float* __restrict__ cosk, const float* __restrict__ sink,
              short* __restrict__ wt)
{
    const int idx = blockIdx.x * 256 + threadIdx.x;  // 0..16383
    const int n = idx >> 7, k = idx & 127;
    const int nn = n & 63, km = k & 63;
    float v;
    if (n < 64) v = (k < 64) ? cosk[n * 64 + k] : -sink[n * 64 + km];
    else        v = (k < 64) ? sink[nn * 64 + k] : cosk[nn * 64 + km];
    wt[idx] = f2bf(v);
}

// Main: out[b,n'] = sum_k A[b,k] * W[k,n'].  One wave = 32 batches
// (two 16-row M-subtiles of 16x16x32 MFMA). A fully preloaded (16 x dwordx4
// in flight = 16 KB/wave); B-frags read from L2-resident wt (no LDS, no sync).
__global__ __launch_bounds__(256, 2)
void ofdm_idft_kernel(const float* __restrict__ eq,
                      const short* __restrict__ wt,
                      float* __restrict__ out)
{
    const int lane = threadIdx.x & 63;
    const int wave = threadIdx.x >> 6;
    const int m = lane & 15;   // M row / N col within tile
    const int q = lane >> 4;   // quad: k-offset for frags, row-group for D
    const int b0 = (blockIdx.x * 4 + wave) * 32;

    const unsigned long long PMASK =
        (1ull << 11) | (1ull << 25) | (1ull << 39) | (1ull << 53);

    // ---- A preload: 16 independent dwordx4, issued back-to-back ----
    float4v x[16];
    const float* a0 = eq + (size_t)(b0 + m) * 128 + q * 8;
    #pragma unroll
    for (int u = 0; u < 2; ++u) {
        const float* a = a0 + u * (16 * 128);
        #pragma unroll
        for (int kk = 0; kk < 4; ++kk) {
            x[u * 8 + kk * 2 + 0] = *(const float4v*)(a + kk * 32);
            x[u * 8 + kk * 2 + 1] = *(const float4v*)(a + kk * 32 + 4);
        }
    }

    // ---- cvt + pilot: A[m][k = kk*32 + q*8 + j] ----
    short8 afr[2][4];
    #pragma unroll
    for (int u = 0; u < 2; ++u) {
        #pragma unroll
        for (int kk = 0; kk < 4; ++kk) {
            short8 f;
            #pragma unroll
            for (int j = 0; j < 8; ++j) {
                float xv = (j < 4) ? x[u * 8 + kk * 2][j] : x[u * 8 + kk * 2 + 1][j - 4];
                const int k = kk * 32 + q * 8 + j;
                if ((PMASK >> (k & 63)) & 1ull)
                    xv = (k < 64) ? 1.0f : 0.0f;   // pilot: real->1, imag->0
                f[j] = f2bf(xv);
            }
            afr[u][kk] = f;
        }
    }

    float4v acc[2][8];
    #pragma unroll
    for (int u = 0; u < 2; ++u)
        #pragma unroll
        for (int nt = 0; nt < 8; ++nt)
            acc[u][nt] = (float4v){0.f, 0.f, 0.f, 0.f};

    // ---- MFMA: B-frags from L2 (wt hot per XCD), shared across both subtiles ----
    #pragma unroll
    for (int kk = 0; kk < 4; ++kk) {
        short8 bfr[8];
        #pragma unroll
        for (int nt = 0; nt < 8; ++nt)
            bfr[nt] = *(const short8*)(wt + (nt * 16 + m) * 128 + kk * 32 + q * 8);
        #pragma unroll
        for (int nt = 0; nt < 8; ++nt) {
            acc[0][nt] = __builtin_amdgcn_mfma_f32_16x16x32_bf16(
                afr[0][kk], bfr[nt], acc[0][nt], 0, 0, 0);
            acc[1][nt] = __builtin_amdgcn_mfma_f32_16x16x32_bf16(
                afr[1][kk], bfr[nt], acc[1][nt], 0, 0, 0);
        }
    }

    // ---- Store: D[row = q*4 + r][col = nt*16 + m]; nt inner so the two
    // 64B halves of each 128B line issue adjacently ----
    #pragma unroll
    for (int u = 0; u < 2; ++u) {
        float* orow = out + (size_t)(b0 + u * 16) * 128;
        #pragma unroll
        for (int r = 0; r < 4; ++r)
            #pragma unroll
            for (int nt = 0; nt < 8; ++nt)
                orow[(size_t)(q * 4 + r) * 128 + nt * 16 + m] = acc[u][nt][r];
    }
}

extern "C" void kernel_launch(void* const* d_in, const int* in_sizes, int n_in,
                              void* d_out, int out_size, void* d_ws, size_t ws_size,
                              hipStream_t stream) {
    const float* eq   = (const float*)d_in[0];
    const float* cosk = (const float*)d_in[1];
    const float* sink = (const float*)d_in[2];
    float* out = (float*)d_out;
    short* wt  = (short*)d_ws;   // 128*128*2 = 32768 B of workspace

    hipLaunchKernelGGL(build_wt, dim3(64), dim3(256), 0, stream, cosk, sink, wt);
    // 2048 blocks * 4 waves * 32 batches = 262144, exact cover
    hipLaunchKernelGGL(ofdm_idft_kernel, dim3(2048), dim3(256), 0, stream,
                       eq, wt, out);
}